// Round 4
// baseline (264.444 us; speedup 1.0000x reference)
//
#include <hip/hip_runtime.h>

#define ALPHA 0.2f

typedef __attribute__((ext_vector_type(4))) short short4v;
typedef __attribute__((ext_vector_type(8))) short short8v;
typedef __attribute__((ext_vector_type(4))) float f32x4;

__device__ __forceinline__ short f2bf(float f) {
  union { float f; unsigned u; } v; v.f = f;
  unsigned r = v.u + 0x7fffu + ((v.u >> 16) & 1u);   // RNE to bf16
  return (short)(r >> 16);
}

// ------------------------------------------------------------------
// K1: h = x@W  -> hT (bf16, [64][8192]);  s1 = h@a1, s2 = h@a2 (fp32)
// also zeroes den[] (k2a accumulates into it atomically).
// ------------------------------------------------------------------
__global__ __launch_bounds__(256) void k1_proj(
    const float* __restrict__ x, const float* __restrict__ W,
    const float* __restrict__ avec,
    short* __restrict__ hT, float* __restrict__ s1, float* __restrict__ s2,
    float* __restrict__ den) {
  __shared__ float xl[32 * 132];
  __shared__ float Wl[128 * 64];
  const int t   = threadIdx.x;
  const int rb  = blockIdx.x;
  const int row = t >> 3;
  const int fg  = t & 7;
  float acc[8];
#pragma unroll
  for (int e = 0; e < 8; e++) acc[e] = 0.f;

  for (int kc = 0; kc < 4; kc++) {
#pragma unroll
    for (int u = 0; u < 4; u++) {
      int lin = t + u * 256;
      int r = lin >> 5, c4 = lin & 31;
      float4 v = *(const float4*)(x + (size_t)(rb * 32 + r) * 512 + kc * 128 + c4 * 4);
      *(float4*)(xl + r * 132 + c4 * 4) = v;
    }
#pragma unroll
    for (int u = 0; u < 8; u++) {
      int lin = t + u * 256;
      int r = lin >> 4, c4 = lin & 15;
      float4 v = *(const float4*)(W + (size_t)(kc * 128 + r) * 64 + c4 * 4);
      *(float4*)(Wl + r * 64 + c4 * 4) = v;
    }
    __syncthreads();
#pragma unroll 8
    for (int k = 0; k < 128; k++) {
      float xv = xl[row * 132 + k];
      float4 w0 = *(const float4*)(Wl + k * 64 + fg * 8);
      float4 w1 = *(const float4*)(Wl + k * 64 + fg * 8 + 4);
      acc[0] = fmaf(xv, w0.x, acc[0]); acc[1] = fmaf(xv, w0.y, acc[1]);
      acc[2] = fmaf(xv, w0.z, acc[2]); acc[3] = fmaf(xv, w0.w, acc[3]);
      acc[4] = fmaf(xv, w1.x, acc[4]); acc[5] = fmaf(xv, w1.y, acc[5]);
      acc[6] = fmaf(xv, w1.z, acc[6]); acc[7] = fmaf(xv, w1.w, acc[7]);
    }
    __syncthreads();
  }

  float p1 = 0.f, p2 = 0.f;
#pragma unroll
  for (int e = 0; e < 8; e++) {
    p1 = fmaf(acc[e], avec[fg * 8 + e], p1);
    p2 = fmaf(acc[e], avec[64 + fg * 8 + e], p2);
  }
  p1 += __shfl_xor(p1, 1, 64); p1 += __shfl_xor(p1, 2, 64); p1 += __shfl_xor(p1, 4, 64);
  p2 += __shfl_xor(p2, 1, 64); p2 += __shfl_xor(p2, 2, 64); p2 += __shfl_xor(p2, 4, 64);
  const int gi = rb * 32 + row;
  if (fg == 0) { s1[gi] = p1; s2[gi] = p2; den[gi] = 0.f; }
#pragma unroll
  for (int e = 0; e < 8; e++)
    hT[(size_t)(fg * 8 + e) * 8192 + gi] = f2bf(acc[e]);
}

// ------------------------------------------------------------------
// K2a: PURE STREAMING exp pass. Grid-linear float4 sweep over adj
// (copy-kernel shaped: whole grid covers a contiguous 8 MB window per
// iteration). Writes P (bf16) in tiled layout [rblk][jblk][64][256];
// per-wave denom reduce + one atomicAdd per row per wave.
// ------------------------------------------------------------------
__global__ __launch_bounds__(256) void k2a_exp(
    const float* __restrict__ adj, const float* __restrict__ s1,
    const float* __restrict__ s2, short* __restrict__ P,
    float* __restrict__ den) {
  int g = blockIdx.x * 256 + threadIdx.x;
  const int lane = threadIdx.x & 63;
#pragma unroll 2
  for (int it = 0; it < 32; ++it, g += 524288) {
    const int row  = g >> 11;          // 2048 float4 per row
    const int col4 = g & 2047;         // wave-uniform row; 64 col4 per wave
    float4 a  = *(const float4*)(adj + ((size_t)g << 2));
    float4 sv = *(const float4*)(s2 + (col4 << 2));
    const float s1v = s1[row];
    float z0 = s1v + sv.x; z0 = fmaxf(z0, ALPHA * z0) * a.x;
    float z1 = s1v + sv.y; z1 = fmaxf(z1, ALPHA * z1) * a.y;
    float z2 = s1v + sv.z; z2 = fmaxf(z2, ALPHA * z2) * a.z;
    float z3 = s1v + sv.w; z3 = fmaxf(z3, ALPHA * z3) * a.w;
    float w0 = __expf(z0), w1 = __expf(z1), w2 = __expf(z2), w3 = __expf(z3);
    short4v pk = { f2bf(w0), f2bf(w1), f2bf(w2), f2bf(w3) };
    *(short4v*)(P + (((size_t)(row >> 6) * 32 + (col4 >> 6)) << 14)
                  + ((row & 63) << 8) + ((col4 & 63) << 2)) = pk;
    float d = (w0 + w1) + (w2 + w3);
    d += __shfl_xor(d, 1, 64); d += __shfl_xor(d, 2, 64);
    d += __shfl_xor(d, 4, 64); d += __shfl_xor(d, 8, 64);
    d += __shfl_xor(d, 16, 64); d += __shfl_xor(d, 32, 64);
    if (lane == 0) atomicAdd(&den[row], d);
  }
}

// ------------------------------------------------------------------
// K2b: num_partial = P @ hT^T via MFMA. Block (rb, ks) reads its P
// slice as CONTIGUOUS tiles (128 KB sequential), A-frags straight from
// global P (no LDS). Depth-2 named-register prefetch of A tiles.
// ------------------------------------------------------------------
__global__ __launch_bounds__(256, 4) void k2b_pv(
    const short* __restrict__ P, const short* __restrict__ hT,
    float* __restrict__ num, const int KS, const int JSPAN) {
  const int t   = threadIdx.x;
  const int wvi = t >> 6;
  const int l   = t & 63;
  const int lq  = l >> 4;
  const int lr  = l & 15;
  const int rb  = blockIdx.x & 127;
  const int ks  = blockIdx.x >> 7;
  const int r0  = rb << 6;
  const int nchunk = JSPAN >> 8;                 // tiles per block (even)
  const int jblk0  = ks * nchunk;
  const int j0     = ks * JSPAN;

  f32x4 acc[4];
#pragma unroll
  for (int fb = 0; fb < 4; fb++) acc[fb] = (f32x4){0.f, 0.f, 0.f, 0.f};

  const short* tb = P + (((size_t)rb * 32 + jblk0) << 14);
  const int aoff  = (wvi * 16 + lr) * 256 + lq * 4;

  short4v A0,A1,A2,A3,A4,A5,A6,A7,A8,A9,A10,A11,A12,A13,A14,A15;
  short4v B0,B1,B2,B3,B4,B5,B6,B7,B8,B9,B10,B11,B12,B13,B14,B15;

#define LDA(S, base) do {                                                    \
    const short* b__ = (base) + aoff;                                        \
    S##0 =*(const short4v*)(b__+0);    S##1 =*(const short4v*)(b__+16);      \
    S##2 =*(const short4v*)(b__+32);   S##3 =*(const short4v*)(b__+48);      \
    S##4 =*(const short4v*)(b__+64);   S##5 =*(const short4v*)(b__+80);      \
    S##6 =*(const short4v*)(b__+96);   S##7 =*(const short4v*)(b__+112);     \
    S##8 =*(const short4v*)(b__+128);  S##9 =*(const short4v*)(b__+144);     \
    S##10=*(const short4v*)(b__+160);  S##11=*(const short4v*)(b__+176);     \
    S##12=*(const short4v*)(b__+192);  S##13=*(const short4v*)(b__+208);     \
    S##14=*(const short4v*)(b__+224);  S##15=*(const short4v*)(b__+240);     \
  } while (0)

#define PVSTEP(AE, AO, kk, jc) do {                                          \
    union { short4v h[2]; short8v v; } au, bu;                               \
    au.h[0] = AE; au.h[1] = AO;                                              \
    _Pragma("unroll")                                                        \
    for (int fb = 0; fb < 4; fb++) {                                         \
      const short* bp = hT + (size_t)(fb * 16 + lr) * 8192 + (jc) +          \
                        (kk) * 32 + lq * 4;                                  \
      bu.h[0] = *(const short4v*)bp;                                         \
      bu.h[1] = *(const short4v*)(bp + 16);                                  \
      acc[fb] = __builtin_amdgcn_mfma_f32_16x16x32_bf16(au.v, bu.v,          \
                                                        acc[fb], 0, 0, 0);   \
    }                                                                        \
  } while (0)

#define PVCHUNK(S, jc) do {                                                  \
    PVSTEP(S##0,  S##1,  0, jc); PVSTEP(S##2,  S##3,  1, jc);                \
    PVSTEP(S##4,  S##5,  2, jc); PVSTEP(S##6,  S##7,  3, jc);                \
    PVSTEP(S##8,  S##9,  4, jc); PVSTEP(S##10, S##11, 5, jc);                \
    PVSTEP(S##12, S##13, 6, jc); PVSTEP(S##14, S##15, 7, jc);                \
  } while (0)

  LDA(A, tb);                                    // chunk 0
  for (int c = 0; c < nchunk; c += 2) {
    LDA(B, tb + (c + 1) * 16384);
    PVCHUNK(A, j0 + c * 256);
    if (c + 2 < nchunk) LDA(A, tb + (c + 2) * 16384);
    PVCHUNK(B, j0 + (c + 1) * 256);
  }
#undef LDA
#undef PVSTEP
#undef PVCHUNK

  float* np = num + (size_t)ks * 524288;
#pragma unroll
  for (int fb = 0; fb < 4; fb++)
#pragma unroll
    for (int r = 0; r < 4; r++)
      np[(size_t)(r0 + wvi * 16 + lq * 4 + r) * 64 + fb * 16 + lr] = acc[fb][r];
}

// ------------------------------------------------------------------
// K3 (main): out = elu( sum_ks num / den )
// ------------------------------------------------------------------
__global__ __launch_bounds__(256) void k3_fin(
    const float* __restrict__ num, const float* __restrict__ den,
    float* __restrict__ out, const int KS) {
  const int idx = blockIdx.x * 256 + threadIdx.x;
  const int row = idx >> 6;
  float n = 0.f;
  for (int ksi = 0; ksi < KS; ksi++) n += num[(size_t)ksi * 524288 + idx];
  float v = n / den[row];
  out[idx] = v > 0.f ? v : (__expf(v) - 1.f);
}

// ==================================================================
// FALLBACK (ws too small for P): R3's fused kernel + per-ks den.
// ==================================================================
__global__ __launch_bounds__(256, 3) void k2_fused(
    const float* __restrict__ adj, const short* __restrict__ hT,
    const float* __restrict__ s1, const float* __restrict__ s2,
    float* __restrict__ num, float* __restrict__ den,
    const int KS, const int JSPAN) {
  __shared__ short At[4][16][272];
  const int t    = threadIdx.x;
  const int wvi  = t >> 6;
  const int l    = t & 63;
  const int lq   = l >> 4;
  const int lr   = l & 15;
  const int rb   = blockIdx.x & 127;
  const int ks   = blockIdx.x >> 7;
  const int r0   = rb << 6;
  const int j0   = ks * JSPAN;
  const int nchunk = JSPAN >> 8;

  float s1r[16];
#pragma unroll
  for (int i = 0; i < 16; i++)
    s1r[i] = __int_as_float(
        __builtin_amdgcn_readfirstlane(__float_as_int(s1[r0 + wvi * 16 + i])));
  float denom_p[16];
#pragma unroll
  for (int i = 0; i < 16; i++) denom_p[i] = 0.f;
  f32x4 acc[4];
#pragma unroll
  for (int fb = 0; fb < 4; fb++) acc[fb] = (f32x4){0.f, 0.f, 0.f, 0.f};
  const float* arow0 = adj + (size_t)(r0 + wvi * 16) * 8192 + j0;

  for (int c = 0; c < nchunk; c++) {
    const int jc = j0 + c * 256;
    float4 av0,av1,av2,av3,av4,av5,av6,av7,av8,av9,av10,av11,av12,av13,av14,av15;
    {
      const float* ab = arow0 + c * 256 + l * 4;
      av0  = *(const float4*)(ab);             av1  = *(const float4*)(ab + 1 * 8192);
      av2  = *(const float4*)(ab + 2 * 8192);  av3  = *(const float4*)(ab + 3 * 8192);
      av4  = *(const float4*)(ab + 4 * 8192);  av5  = *(const float4*)(ab + 5 * 8192);
      av6  = *(const float4*)(ab + 6 * 8192);  av7  = *(const float4*)(ab + 7 * 8192);
      av8  = *(const float4*)(ab + 8 * 8192);  av9  = *(const float4*)(ab + 9 * 8192);
      av10 = *(const float4*)(ab + 10 * 8192); av11 = *(const float4*)(ab + 11 * 8192);
      av12 = *(const float4*)(ab + 12 * 8192); av13 = *(const float4*)(ab + 13 * 8192);
      av14 = *(const float4*)(ab + 14 * 8192); av15 = *(const float4*)(ab + 15 * 8192);
    }
    float4 s2v = *(const float4*)(s2 + jc + l * 4);
#define K2_EXPROW(I, AV) do {                                                 \
      float z0 = s1r[I] + s2v.x; z0 = fmaxf(z0, ALPHA * z0) * AV.x;           \
      float z1 = s1r[I] + s2v.y; z1 = fmaxf(z1, ALPHA * z1) * AV.y;           \
      float z2 = s1r[I] + s2v.z; z2 = fmaxf(z2, ALPHA * z2) * AV.z;           \
      float z3 = s1r[I] + s2v.w; z3 = fmaxf(z3, ALPHA * z3) * AV.w;           \
      float w0 = __expf(z0), w1 = __expf(z1), w2 = __expf(z2), w3 = __expf(z3);\
      denom_p[I] += (w0 + w1) + (w2 + w3);                                    \
      short4v pk = { f2bf(w0), f2bf(w1), f2bf(w2), f2bf(w3) };                \
      *(short4v*)(&At[wvi][I][l * 4]) = pk;                                   \
    } while (0)
    K2_EXPROW(0, av0);   K2_EXPROW(1, av1);   K2_EXPROW(2, av2);
    K2_EXPROW(3, av3);   K2_EXPROW(4, av4);   K2_EXPROW(5, av5);
    K2_EXPROW(6, av6);   K2_EXPROW(7, av7);   K2_EXPROW(8, av8);
    K2_EXPROW(9, av9);   K2_EXPROW(10, av10); K2_EXPROW(11, av11);
    K2_EXPROW(12, av12); K2_EXPROW(13, av13); K2_EXPROW(14, av14);
    K2_EXPROW(15, av15);
#undef K2_EXPROW
#pragma unroll
    for (int kk = 0; kk < 8; kk++) {
      const int k0 = kk * 32;
      union { short4v h[2]; short8v v; } au, bu;
      au.h[0] = *(const short4v*)(&At[wvi][lr][k0 + lq * 4]);
      au.h[1] = *(const short4v*)(&At[wvi][lr][k0 + 16 + lq * 4]);
#pragma unroll
      for (int fb = 0; fb < 4; fb++) {
        const short* bp = hT + (size_t)(fb * 16 + lr) * 8192 + jc + k0 + lq * 4;
        bu.h[0] = *(const short4v*)(bp);
        bu.h[1] = *(const short4v*)(bp + 16);
        acc[fb] = __builtin_amdgcn_mfma_f32_16x16x32_bf16(au.v, bu.v,
                                                          acc[fb], 0, 0, 0);
      }
    }
  }
#pragma unroll
  for (int i = 0; i < 16; i++) {
    float d = denom_p[i];
    d += __shfl_xor(d, 1, 64); d += __shfl_xor(d, 2, 64);
    d += __shfl_xor(d, 4, 64); d += __shfl_xor(d, 8, 64);
    d += __shfl_xor(d, 16, 64); d += __shfl_xor(d, 32, 64);
    if (l == 0) den[(size_t)ks * 8192 + r0 + wvi * 16 + i] = d;
  }
  float* np = num + (size_t)ks * 524288;
#pragma unroll
  for (int fb = 0; fb < 4; fb++)
#pragma unroll
    for (int r = 0; r < 4; r++)
      np[(size_t)(r0 + wvi * 16 + lq * 4 + r) * 64 + fb * 16 + lr] = acc[fb][r];
}

__global__ __launch_bounds__(256) void k3_fb(
    const float* __restrict__ num, const float* __restrict__ den,
    float* __restrict__ out, const int KS) {
  const int idx = blockIdx.x * 256 + threadIdx.x;
  const int row = idx >> 6;
  float n = 0.f, d = 0.f;
  for (int ksi = 0; ksi < KS; ksi++) {
    n += num[(size_t)ksi * 524288 + idx];
    d += den[ksi * 8192 + row];
  }
  float v = n / d;
  out[idx] = v > 0.f ? v : (__expf(v) - 1.f);
}

extern "C" void kernel_launch(void* const* d_in, const int* in_sizes, int n_in,
                              void* d_out, int out_size, void* d_ws, size_t ws_size,
                              hipStream_t stream) {
  const float* x   = (const float*)d_in[0];
  const float* adj = (const float*)d_in[1];
  const float* W   = (const float*)d_in[2];
  const float* av  = (const float*)d_in[3];
  float* out = (float*)d_out;
  char* ws = (char*)d_ws;

  short* hT  = (short*)ws;                                 // 1 MB
  float* s1  = (float*)(ws + (1 << 20));                   // 32 KB
  float* s2  = (float*)(ws + (1 << 20) + 32768);           // 32 KB
  float* den = (float*)(ws + (1 << 20) + 65536);           // 32 KB (main path)

  // main-path layout: P at 2 MB (128 MB), num after P (16 MB)
  short* P   = (short*)(ws + (2u << 20));
  float* num = (float*)(ws + (2u << 20) + 134217728u);
  const size_t need_main = (2u << 20) + 134217728u + 8u * 2097152u;

  hipLaunchKernelGGL(k1_proj, dim3(256), dim3(256), 0, stream,
                     x, W, av, hT, s1, s2, den);

  if (ws_size >= need_main) {
    hipLaunchKernelGGL(k2a_exp, dim3(2048), dim3(256), 0, stream,
                       adj, s1, s2, P, den);
    hipLaunchKernelGGL(k2b_pv, dim3(1024), dim3(256), 0, stream,
                       P, hT, num, 8, 1024);
    hipLaunchKernelGGL(k3_fin, dim3(2048), dim3(256), 0, stream,
                       num, den, out, 8);
  } else {
    float* numf = (float*)(ws + (1 << 20) + 65536 + 32768);
    int KS = 8;
    while (KS > 1) {
      size_t need = (size_t)(1 << 20) + 65536 + 32768 +
                    (size_t)KS * (524288u * 4u + 32768u);
      if (need <= ws_size) break;
      KS >>= 1;
    }
    float* denf = numf + (size_t)KS * 524288;
    hipLaunchKernelGGL(k2_fused, dim3(128 * KS), dim3(256), 0, stream,
                       adj, hT, s1, s2, numf, denf, KS, 8192 / KS);
    hipLaunchKernelGGL(k3_fb, dim3(2048), dim3(256), 0, stream,
                       numf, denf, out, KS);
  }
}

// Round 5
// 125.944 us; speedup vs baseline: 2.0997x; 2.0997x over previous
//
#include <hip/hip_runtime.h>

#define ALPHA 0.2f

typedef __attribute__((ext_vector_type(2))) short short2v;
typedef __attribute__((ext_vector_type(4))) short short4v;
typedef __attribute__((ext_vector_type(8))) short short8v;
typedef __attribute__((ext_vector_type(4))) float f32x4;

__device__ __forceinline__ short f2bf(float f) {
  union { float f; unsigned u; } v; v.f = f;
  unsigned r = v.u + 0x7fffu + ((v.u >> 16) & 1u);   // RNE to bf16
  return (short)(r >> 16);
}

// ------------------------------------------------------------------
// K1: h = x@W  -> hT (bf16, [64][8192]);  s1 = h@a1, s2 = h@a2 (fp32)
// ------------------------------------------------------------------
__global__ __launch_bounds__(256) void k1_proj(
    const float* __restrict__ x, const float* __restrict__ W,
    const float* __restrict__ avec,
    short* __restrict__ hT, float* __restrict__ s1, float* __restrict__ s2) {
  __shared__ float xl[32 * 132];
  __shared__ float Wl[128 * 64];
  const int t   = threadIdx.x;
  const int rb  = blockIdx.x;
  const int row = t >> 3;
  const int fg  = t & 7;
  float acc[8];
#pragma unroll
  for (int e = 0; e < 8; e++) acc[e] = 0.f;

  for (int kc = 0; kc < 4; kc++) {
#pragma unroll
    for (int u = 0; u < 4; u++) {
      int lin = t + u * 256;
      int r = lin >> 5, c4 = lin & 31;
      float4 v = *(const float4*)(x + (size_t)(rb * 32 + r) * 512 + kc * 128 + c4 * 4);
      *(float4*)(xl + r * 132 + c4 * 4) = v;
    }
#pragma unroll
    for (int u = 0; u < 8; u++) {
      int lin = t + u * 256;
      int r = lin >> 4, c4 = lin & 15;
      float4 v = *(const float4*)(W + (size_t)(kc * 128 + r) * 64 + c4 * 4);
      *(float4*)(Wl + r * 64 + c4 * 4) = v;
    }
    __syncthreads();
#pragma unroll 8
    for (int k = 0; k < 128; k++) {
      float xv = xl[row * 132 + k];
      float4 w0 = *(const float4*)(Wl + k * 64 + fg * 8);
      float4 w1 = *(const float4*)(Wl + k * 64 + fg * 8 + 4);
      acc[0] = fmaf(xv, w0.x, acc[0]); acc[1] = fmaf(xv, w0.y, acc[1]);
      acc[2] = fmaf(xv, w0.z, acc[2]); acc[3] = fmaf(xv, w0.w, acc[3]);
      acc[4] = fmaf(xv, w1.x, acc[4]); acc[5] = fmaf(xv, w1.y, acc[5]);
      acc[6] = fmaf(xv, w1.z, acc[6]); acc[7] = fmaf(xv, w1.w, acc[7]);
    }
    __syncthreads();
  }

  float p1 = 0.f, p2 = 0.f;
#pragma unroll
  for (int e = 0; e < 8; e++) {
    p1 = fmaf(acc[e], avec[fg * 8 + e], p1);
    p2 = fmaf(acc[e], avec[64 + fg * 8 + e], p2);
  }
  p1 += __shfl_xor(p1, 1, 64); p1 += __shfl_xor(p1, 2, 64); p1 += __shfl_xor(p1, 4, 64);
  p2 += __shfl_xor(p2, 1, 64); p2 += __shfl_xor(p2, 2, 64); p2 += __shfl_xor(p2, 4, 64);
  const int gi = rb * 32 + row;
  if (fg == 0) { s1[gi] = p1; s2[gi] = p2; }
#pragma unroll
  for (int e = 0; e < 8; e++)
    hT[(size_t)(fg * 8 + e) * 8192 + gi] = f2bf(acc[e]);
}

// ------------------------------------------------------------------
// K2 v5: fused, ZERO scattered global loads.
//  - chunk = 128 j-cols; hT chunk (64x128) staged to LDS via contiguous
//    512B wave-loads (wave w stages f-rows w*16..w*16+15), padded
//    stride 136 -> frag ds_reads near-conflict-free.
//  - MFMA A/B frags: single ds_read_b128 each, k-permutation k=lq*8+e
//    (identical for A and B -> cancels).
//  - adj: 16 rows x 512B contiguous per instr, depth-2 ping/pong regs.
//  - 2 barriers/chunk; prefetch issued right after barrier-1.
// ------------------------------------------------------------------
__global__ __launch_bounds__(256, 3) void k2_attn(
    const float* __restrict__ adj, const short* __restrict__ hT,
    const float* __restrict__ s1, const float* __restrict__ s2,
    float* __restrict__ num, float* __restrict__ den,
    const int KS, const int JSPAN) {
  __shared__ short hTl[64 * 136];     // 17 KB
  __shared__ short Pl[4][16 * 136];   // 17 KB (wave-private slices)
  const int t    = threadIdx.x;
  const int wvi  = t >> 6;
  const int l    = t & 63;
  const int lq   = l >> 4;            // 0..3
  const int lr   = l & 15;            // 0..15
  const int rb   = blockIdx.x & 127;
  const int ks   = blockIdx.x >> 7;
  const int r0   = rb << 6;
  const int j0   = ks * JSPAN;
  const int nchunk = JSPAN >> 7;      // pow2 (KS=8 -> 8)

  float s1r[16];
#pragma unroll
  for (int i = 0; i < 16; i++)
    s1r[i] = __int_as_float(
        __builtin_amdgcn_readfirstlane(__float_as_int(s1[r0 + wvi * 16 + i])));

  float denom_p[16];
#pragma unroll
  for (int i = 0; i < 16; i++) denom_p[i] = 0.f;

  f32x4 acc[4];
#pragma unroll
  for (int fb = 0; fb < 4; fb++) acc[fb] = (f32x4){0.f, 0.f, 0.f, 0.f};

  const float* arow0 = adj + (size_t)(r0 + wvi * 16) * 8192 + j0;
  const short* hrow  = hT + (size_t)(wvi * 16) * 8192 + j0;
  const float* s2p   = s2 + j0;

  short2v Sh0,Sh1,Sh2,Sh3,Sh4,Sh5,Sh6,Sh7,Sh8,Sh9,Sh10,Sh11,Sh12,Sh13,Sh14,Sh15;
  float2  A0,A1,A2,A3,A4,A5,A6,A7,A8,A9,A10,A11,A12,A13,A14,A15;
  float2  B0,B1,B2,B3,B4,B5,B6,B7,B8,B9,B10,B11,B12,B13,B14,B15;
  float2  s2A, s2B;

#define LDH(JOFF) do { const short* hb__ = hrow + (JOFF) + l * 2;             \
    Sh0  = *(const short2v*)(hb__);              Sh1  = *(const short2v*)(hb__ + 1 * 8192); \
    Sh2  = *(const short2v*)(hb__ + 2 * 8192);   Sh3  = *(const short2v*)(hb__ + 3 * 8192); \
    Sh4  = *(const short2v*)(hb__ + 4 * 8192);   Sh5  = *(const short2v*)(hb__ + 5 * 8192); \
    Sh6  = *(const short2v*)(hb__ + 6 * 8192);   Sh7  = *(const short2v*)(hb__ + 7 * 8192); \
    Sh8  = *(const short2v*)(hb__ + 8 * 8192);   Sh9  = *(const short2v*)(hb__ + 9 * 8192); \
    Sh10 = *(const short2v*)(hb__ + 10 * 8192);  Sh11 = *(const short2v*)(hb__ + 11 * 8192); \
    Sh12 = *(const short2v*)(hb__ + 12 * 8192);  Sh13 = *(const short2v*)(hb__ + 13 * 8192); \
    Sh14 = *(const short2v*)(hb__ + 14 * 8192);  Sh15 = *(const short2v*)(hb__ + 15 * 8192); \
  } while (0)

#define LDADJ(S, JOFF) do { const float* ab__ = arow0 + (JOFF) + l * 2;       \
    S##0  = *(const float2*)(ab__);              S##1  = *(const float2*)(ab__ + 1 * 8192); \
    S##2  = *(const float2*)(ab__ + 2 * 8192);   S##3  = *(const float2*)(ab__ + 3 * 8192); \
    S##4  = *(const float2*)(ab__ + 4 * 8192);   S##5  = *(const float2*)(ab__ + 5 * 8192); \
    S##6  = *(const float2*)(ab__ + 6 * 8192);   S##7  = *(const float2*)(ab__ + 7 * 8192); \
    S##8  = *(const float2*)(ab__ + 8 * 8192);   S##9  = *(const float2*)(ab__ + 9 * 8192); \
    S##10 = *(const float2*)(ab__ + 10 * 8192);  S##11 = *(const float2*)(ab__ + 11 * 8192); \
    S##12 = *(const float2*)(ab__ + 12 * 8192);  S##13 = *(const float2*)(ab__ + 13 * 8192); \
    S##14 = *(const float2*)(ab__ + 14 * 8192);  S##15 = *(const float2*)(ab__ + 15 * 8192); \
  } while (0)

#define EXPROW(I, AV, S2V) do {                                               \
    float z0 = s1r[I] + S2V.x; z0 = fmaxf(z0, ALPHA * z0) * AV.x;             \
    float z1 = s1r[I] + S2V.y; z1 = fmaxf(z1, ALPHA * z1) * AV.y;             \
    float w0 = __expf(z0), w1 = __expf(z1);                                   \
    denom_p[I] += w0 + w1;                                                    \
    short2v pk = { f2bf(w0), f2bf(w1) };                                      \
    *(short2v*)(&Pl[wvi][(I) * 136 + l * 2]) = pk;                            \
  } while (0)

#define K2_BODY(AS, S2, CIDX) do {                                            \
    { short* hw__ = hTl + (wvi * 16) * 136 + l * 2;                           \
      *(short2v*)(hw__ + 0 * 136)  = Sh0;  *(short2v*)(hw__ + 1 * 136)  = Sh1;  \
      *(short2v*)(hw__ + 2 * 136)  = Sh2;  *(short2v*)(hw__ + 3 * 136)  = Sh3;  \
      *(short2v*)(hw__ + 4 * 136)  = Sh4;  *(short2v*)(hw__ + 5 * 136)  = Sh5;  \
      *(short2v*)(hw__ + 6 * 136)  = Sh6;  *(short2v*)(hw__ + 7 * 136)  = Sh7;  \
      *(short2v*)(hw__ + 8 * 136)  = Sh8;  *(short2v*)(hw__ + 9 * 136)  = Sh9;  \
      *(short2v*)(hw__ + 10 * 136) = Sh10; *(short2v*)(hw__ + 11 * 136) = Sh11; \
      *(short2v*)(hw__ + 12 * 136) = Sh12; *(short2v*)(hw__ + 13 * 136) = Sh13; \
      *(short2v*)(hw__ + 14 * 136) = Sh14; *(short2v*)(hw__ + 15 * 136) = Sh15; } \
    __syncthreads();                                                          \
    { const int jn__ = (((CIDX) + 1) & (nchunk - 1)) * 128; LDH(jn__); }      \
    EXPROW(0, AS##0, S2);   EXPROW(1, AS##1, S2);   EXPROW(2, AS##2, S2);     \
    EXPROW(3, AS##3, S2);   EXPROW(4, AS##4, S2);   EXPROW(5, AS##5, S2);     \
    EXPROW(6, AS##6, S2);   EXPROW(7, AS##7, S2);   EXPROW(8, AS##8, S2);     \
    EXPROW(9, AS##9, S2);   EXPROW(10, AS##10, S2); EXPROW(11, AS##11, S2);   \
    EXPROW(12, AS##12, S2); EXPROW(13, AS##13, S2); EXPROW(14, AS##14, S2);   \
    EXPROW(15, AS##15, S2);                                                   \
    { const int ja__ = (((CIDX) + 2) & (nchunk - 1)) * 128;                   \
      LDADJ(AS, ja__);                                                        \
      S2 = *(const float2*)(s2p + ja__ + l * 2); }                            \
    _Pragma("unroll")                                                         \
    for (int kk = 0; kk < 4; kk++) {                                          \
      const short8v au = *(const short8v*)(&Pl[wvi][lr * 136 + kk * 32 + lq * 8]); \
      _Pragma("unroll")                                                       \
      for (int fb = 0; fb < 4; fb++) {                                        \
        const short8v bu = *(const short8v*)(&hTl[(fb * 16 + lr) * 136 + kk * 32 + lq * 8]); \
        acc[fb] = __builtin_amdgcn_mfma_f32_16x16x32_bf16(au, bu, acc[fb], 0, 0, 0); \
      }                                                                       \
    }                                                                         \
    __syncthreads();                                                          \
  } while (0)

  // prologue: chunk 0 staged, adj chunks 0/1 in flight
  LDH(0);
  LDADJ(A, 0);   s2A = *(const float2*)(s2p + l * 2);
  LDADJ(B, 128); s2B = *(const float2*)(s2p + 128 + l * 2);

  for (int cc = 0; cc < nchunk; cc += 2) {
    K2_BODY(A, s2A, cc);
    K2_BODY(B, s2B, cc + 1);
  }
#undef LDH
#undef LDADJ
#undef EXPROW
#undef K2_BODY

  // epilogue: partial denominators and numerators
#pragma unroll
  for (int i = 0; i < 16; i++) {
    float d = denom_p[i];
    d += __shfl_xor(d, 1, 64); d += __shfl_xor(d, 2, 64);
    d += __shfl_xor(d, 4, 64); d += __shfl_xor(d, 8, 64);
    d += __shfl_xor(d, 16, 64); d += __shfl_xor(d, 32, 64);
    if (l == 0) den[(size_t)ks * 8192 + r0 + wvi * 16 + i] = d;
  }
  float* np = num + (size_t)ks * 524288;
#pragma unroll
  for (int fb = 0; fb < 4; fb++)
#pragma unroll
    for (int r = 0; r < 4; r++)
      np[(size_t)(r0 + wvi * 16 + lq * 4 + r) * 64 + fb * 16 + lr] = acc[fb][r];
}

// ------------------------------------------------------------------
// K3: out = elu( sum_ks num / sum_ks den )
// ------------------------------------------------------------------
__global__ __launch_bounds__(256) void k3_norm(
    const float* __restrict__ num, const float* __restrict__ den,
    float* __restrict__ out, const int KS) {
  const int idx = blockIdx.x * 256 + threadIdx.x;   // 0..524287
  const int row = idx >> 6;
  float n = 0.f, d = 0.f;
  for (int ksi = 0; ksi < KS; ksi++) {
    n += num[(size_t)ksi * 524288 + idx];
    d += den[ksi * 8192 + row];
  }
  float v = n / d;
  out[idx] = v > 0.f ? v : (__expf(v) - 1.f);
}

extern "C" void kernel_launch(void* const* d_in, const int* in_sizes, int n_in,
                              void* d_out, int out_size, void* d_ws, size_t ws_size,
                              hipStream_t stream) {
  const float* x   = (const float*)d_in[0];
  const float* adj = (const float*)d_in[1];
  const float* W   = (const float*)d_in[2];
  const float* av  = (const float*)d_in[3];
  float* out = (float*)d_out;
  char* ws = (char*)d_ws;

  short* hT = (short*)ws;                                  // 1 MB
  float* s1 = (float*)(ws + (1 << 20));                    // 32 KB
  float* s2 = (float*)(ws + (1 << 20) + 32768);            // 32 KB
  float* num = (float*)(ws + (1 << 20) + 65536);
  int KS = 8;
  while (KS > 1) {
    size_t need = (size_t)(1 << 20) + 65536 + (size_t)KS * (524288u * 4u + 32768u);
    if (need <= ws_size) break;
    KS >>= 1;
  }
  float* den = num + (size_t)KS * 524288;

  hipLaunchKernelGGL(k1_proj, dim3(256), dim3(256), 0, stream, x, W, av, hT, s1, s2);
  hipLaunchKernelGGL(k2_attn, dim3(128 * KS), dim3(256), 0, stream,
                     adj, hT, s1, s2, num, den, KS, 8192 / KS);
  hipLaunchKernelGGL(k3_norm, dim3(2048), dim3(256), 0, stream, num, den, out, KS);
}